// Round 18
// baseline (955.710 us; speedup 1.0000x reference)
//
#include <hip/hip_runtime.h>
#include <hip/hip_fp16.h>

#define NB   256
#define TT   1024
#define II   64
#define NT   768

typedef _Float16 f16;
typedef _Float16 f16x4 __attribute__((ext_vector_type(4)));
typedef _Float16 hf8 __attribute__((ext_vector_type(8)));
typedef float    ff4 __attribute__((ext_vector_type(4)));

__device__ __forceinline__ float rcp_fast(float x){
    float r; asm("v_rcp_f32 %0, %1" : "=v"(r) : "v"(x)); return r;
}
__device__ __forceinline__ float exp2_fast(float x){
    float r; asm("v_exp_f32 %0, %1" : "=v"(r) : "v"(x)); return r;
}
__device__ __forceinline__ float sigm(float x){
    return rcp_fast(1.0f + exp2_fast(x * -1.44269504f));
}
__device__ __forceinline__ float tanh_f(float x){
    return fmaf(-2.0f, rcp_fast(1.0f + exp2_fast(x * 2.88539008f)), 1.0f);
}
__device__ __forceinline__ hf8 ldw8(const float* src){
    float4 a = *(const float4*)src;
    float4 b = *(const float4*)(src + 4);
    hf8 r;
    r[0]=(f16)a.x; r[1]=(f16)a.y; r[2]=(f16)a.z; r[3]=(f16)a.w;
    r[4]=(f16)b.x; r[5]=(f16)b.y; r[6]=(f16)b.z; r[7]=(f16)b.w;
    return r;
}

// R18: 12 waves (3/SIMD), 4 tiles/wave, NO xg GEMM path (its ~70 live regs
// were the R16/R17 spill cause). Per-thread ~155 regs <= 170 cap.
// Waves 0-7: L1, tiles 4w..4w+3, K=192 over [x(2kt); h1(4kt)].
// Waves 8-11: L2, tiles 4wv.., K=192 over [h1(4kt); h2(2kt)], setprio cluster.
// Per SIMD {L1,L1,L2}: 72 MFMA/step; 3-way TLP hides VALU/LDS tails.
// Gate-interleaved tiles (verified R5-R17): gate-row R = (rho&3)*H + 4*tau
// + (rho>>2); C/D row = kg*4+reg => lane (kg,rho) holds gates i,f,g,o of
// unit 4*tau+kg; lanes rho<4 select tile i=rho (2-level cndmask tree),
// bias added post-select from 4 per-lane scalars.
// x: xchunk[64][64] f16 ring (R10-proven), 32 steps staged per 32 steps.

__launch_bounds__(NT, 3)
__global__ void lstm_mfma(const float* __restrict__ x,
                          const float* __restrict__ Wih1, const float* __restrict__ Whh1,
                          const float* __restrict__ bih1, const float* __restrict__ bhh1,
                          const float* __restrict__ Wih2, const float* __restrict__ Whh2,
                          const float* __restrict__ bih2, const float* __restrict__ bhh2,
                          const float* __restrict__ W1,   const float* __restrict__ b1,
                          const float* __restrict__ W2,   const float* __restrict__ b2,
                          float* __restrict__ out)
{
    __shared__ __align__(16) f16 xchunk[64][II];   // 8 KB
    __shared__ __align__(16) f16 h1buf[2][128];
    __shared__ __align__(16) f16 h2buf[2][64];
    __shared__ float headbuf[32];

    const int j    = threadIdx.x;      // 0..767
    const int b    = blockIdx.x;
    const int wave = j >> 6;           // 0..11
    const int lane = j & 63;
    const int rho  = lane & 15;
    const int kg   = lane >> 4;        // 0..3
    const bool l2w = (wave >= 8);
    const int  wv  = l2w ? (wave - 8) : wave;

    const float* xb = x + (size_t)b * TT * II;

    // ---------- one-time: A fragments + post-select bias scalars ----------
    hf8 A[24];                          // A[i*6+kt], i<4
    float bl0, bl1, bl2, bl3;
    if (!l2w){
        #pragma unroll
        for (int i = 0; i < 4; ++i){
            const int tau = 4*wv + i;
            const int R   = (rho & 3)*128 + 4*tau + (rho >> 2);
            #pragma unroll
            for (int kt = 0; kt < 6; ++kt)
                A[i*6 + kt] = ldw8((kt < 2) ? (Wih1 + R*64  + 32*kt     + kg*8)
                                            : (Whh1 + R*128 + 32*(kt-2) + kg*8));
        }
        const int u1 = 4*(4*wv + (rho & 3)) + kg;   // own unit (clamped dup)
        bl0 = bih1[u1]        + bhh1[u1];
        bl1 = bih1[128 + u1]  + bhh1[128 + u1];
        bl2 = bih1[256 + u1]  + bhh1[256 + u1];
        bl3 = bih1[384 + u1]  + bhh1[384 + u1];
    } else {
        #pragma unroll
        for (int i = 0; i < 4; ++i){
            const int tau2 = 4*wv + i;
            const int R    = (rho & 3)*64 + 4*tau2 + (rho >> 2);
            #pragma unroll
            for (int kt = 0; kt < 6; ++kt)
                A[i*6 + kt] = ldw8((kt < 4) ? (Wih2 + R*128 + 32*kt     + kg*8)
                                            : (Whh2 + R*64  + 32*(kt-4) + kg*8));
        }
        const int u2 = 4*(4*wv + (rho & 3)) + kg;
        bl0 = bih2[u2]        + bhh2[u2];
        bl1 = bih2[64 + u2]   + bhh2[64 + u2];
        bl2 = bih2[128 + u2]  + bhh2[128 + u2];
        bl3 = bih2[192 + u2]  + bhh2[192 + u2];
    }

    // prologue: stage steps 0..31 (512 float4, threads 0..511); zero h
    if (j < 512){
        float4 v = ((const float4*)xb)[j];
        f16x4 w; w[0]=(f16)v.x; w[1]=(f16)v.y; w[2]=(f16)v.z; w[3]=(f16)v.w;
        *(f16x4*)&xchunk[j >> 4][(j & 15)*4] = w;
    }
    if (j < 128) h1buf[0][j] = (f16)0.0f;
    if (j < 64)  h2buf[0][j] = (f16)0.0f;
    __syncthreads();

    const ff4 zz = {0.0f, 0.0f, 0.0f, 0.0f};
    float c = 0.0f;
    int cur = 0;
    for (int t = 0; t < TT; ++t){
        // chunk staging: once per 32 steps, issue loads early (threads <512)
        const bool stage = ((t & 31) == 0) && (t + 32 < TT) && (j < 512);
        float4 sv;
        if (stage)
            sv = ((const float4*)(xb + (size_t)(t + 32)*II))[j];

        const f16* h1c = h1buf[cur];
        ff4 acc[4];
        ff4 qd;
        if (!l2w){
            const f16* xr = xchunk[t & 63];
            hf8 bf0 = *(const hf8*)(xr       + kg*8);
            hf8 bf1 = *(const hf8*)(xr + 32  + kg*8);
            hf8 bf2 = *(const hf8*)(h1c      + kg*8);
            hf8 bf3 = *(const hf8*)(h1c + 32 + kg*8);
            hf8 bf4 = *(const hf8*)(h1c + 64 + kg*8);
            hf8 bf5 = *(const hf8*)(h1c + 96 + kg*8);
            #pragma unroll
            for (int i = 0; i < 4; ++i)
                acc[i] = __builtin_amdgcn_mfma_f32_16x16x32_f16(A[i*6+0], bf0, zz, 0, 0, 0);
            #pragma unroll
            for (int kt = 1; kt < 6; ++kt){
                hf8 bb = (kt==1)?bf1:(kt==2)?bf2:(kt==3)?bf3:(kt==4)?bf4:bf5;
                #pragma unroll
                for (int i = 0; i < 4; ++i)
                    acc[i] = __builtin_amdgcn_mfma_f32_16x16x32_f16(A[i*6+kt], bb, acc[i], 0, 0, 0);
            }
        } else {
            const f16* h2c = h2buf[cur];
            hf8 bf0 = *(const hf8*)(h1c      + kg*8);
            hf8 bf1 = *(const hf8*)(h1c + 32 + kg*8);
            hf8 bf2 = *(const hf8*)(h1c + 64 + kg*8);
            hf8 bf3 = *(const hf8*)(h1c + 96 + kg*8);
            hf8 bf4 = *(const hf8*)(h2c      + kg*8);
            hf8 bf5 = *(const hf8*)(h2c + 32 + kg*8);
            __builtin_amdgcn_s_setprio(1);     // T5: L2 staggers vs L1 pair
            #pragma unroll
            for (int i = 0; i < 4; ++i)
                acc[i] = __builtin_amdgcn_mfma_f32_16x16x32_f16(A[i*6+0], bf0, zz, 0, 0, 0);
            #pragma unroll
            for (int kt = 1; kt < 6; ++kt){
                hf8 bb = (kt==1)?bf1:(kt==2)?bf2:(kt==3)?bf3:(kt==4)?bf4:bf5;
                #pragma unroll
                for (int i = 0; i < 4; ++i)
                    acc[i] = __builtin_amdgcn_mfma_f32_16x16x32_f16(A[i*6+kt], bb, acc[i], 0, 0, 0);
            }
            __builtin_amdgcn_s_setprio(0);
        }

        // ---- select own tile's quad (2-level cndmask tree) + bias ----
        {
            ff4 s0 = (rho & 1) ? acc[1] : acc[0];
            ff4 s1 = (rho & 1) ? acc[3] : acc[2];
            qd     = (rho & 2) ? s1 : s0;
        }

        // ---- in-lane activation ----
        if (!l2w){
            float ig = sigm(qd[0] + bl0);
            float fg = sigm(qd[1] + bl1);
            float gg = tanh_f(qd[2] + bl2);
            float og = sigm(qd[3] + bl3);
            c = fg*c + ig*gg;
            float hv = og * tanh_f(c);
            if (rho < 4) h1buf[cur ^ 1][4*(4*wv + rho) + kg] = (f16)hv;
        } else {
            float hv;
            if (t > 0){
                float ig = sigm(qd[0] + bl0);
                float fg = sigm(qd[1] + bl1);
                float gg = tanh_f(qd[2] + bl2);
                float og = sigm(qd[3] + bl3);
                c = fg*c + ig*gg;
                hv = og * tanh_f(c);
            } else {
                hv = 0.0f;                 // h2_{-1}=0, c2 untouched
            }
            if (rho < 4) h2buf[cur ^ 1][4*(4*wv + rho) + kg] = (f16)hv;
        }

        // staging publish (vm-wait lands here, overlapped with step compute)
        if (stage){
            f16x4 w; w[0]=(f16)sv.x; w[1]=(f16)sv.y; w[2]=(f16)sv.z; w[3]=(f16)sv.w;
            *(f16x4*)&xchunk[((t + 32) & 63) + (j >> 4)][(j & 15)*4] = w;
        }
        __syncthreads();
        cur ^= 1;
    }
    // after loop: cur==0; h1buf[0]=h1_{TT-1}, h2buf[0]=h2_{TT-2}

    // ---- epilogue: L2 step TT-1 (waves 8-11) ----
    if (l2w){
        const f16* h1c = h1buf[0];
        const f16* h2c = h2buf[0];
        hf8 bf0 = *(const hf8*)(h1c      + kg*8);
        hf8 bf1 = *(const hf8*)(h1c + 32 + kg*8);
        hf8 bf2 = *(const hf8*)(h1c + 64 + kg*8);
        hf8 bf3 = *(const hf8*)(h1c + 96 + kg*8);
        hf8 bf4 = *(const hf8*)(h2c      + kg*8);
        hf8 bf5 = *(const hf8*)(h2c + 32 + kg*8);
        ff4 acc[4];
        const ff4 zz2 = {0.0f, 0.0f, 0.0f, 0.0f};
        #pragma unroll
        for (int i = 0; i < 4; ++i)
            acc[i] = __builtin_amdgcn_mfma_f32_16x16x32_f16(A[i*6+0], bf0, zz2, 0, 0, 0);
        #pragma unroll
        for (int kt = 1; kt < 6; ++kt){
            hf8 bb = (kt==1)?bf1:(kt==2)?bf2:(kt==3)?bf3:(kt==4)?bf4:bf5;
            #pragma unroll
            for (int i = 0; i < 4; ++i)
                acc[i] = __builtin_amdgcn_mfma_f32_16x16x32_f16(A[i*6+kt], bb, acc[i], 0, 0, 0);
        }
        ff4 s0 = (rho & 1) ? acc[1] : acc[0];
        ff4 s1 = (rho & 1) ? acc[3] : acc[2];
        ff4 qd = (rho & 2) ? s1 : s0;
        float ig = sigm(qd[0] + bl0);
        float fg = sigm(qd[1] + bl1);
        float gg = tanh_f(qd[2] + bl2);
        float og = sigm(qd[3] + bl3);
        c = fg*c + ig*gg;
        float hv = og * tanh_f(c);
        if (rho < 4) h2buf[1][4*(4*wv + rho) + kg] = (f16)hv;
    }
    __syncthreads();

    // ---- MLP head (final h2 in h2buf[1]) ----
    if (j < 32){
        float a = b1[j];
        const float* w = W1 + j*64;
        #pragma unroll
        for (int k = 0; k < 64; ++k) a = fmaf(w[k], (float)h2buf[1][k], a);
        headbuf[j] = sigm(a);
    }
    __syncthreads();
    if (j == 0){
        float a = b2[0];
        #pragma unroll
        for (int k = 0; k < 32; ++k) a = fmaf(W2[k], headbuf[k], a);
        out[b] = sigm(a);
    }
}

extern "C" void kernel_launch(void* const* d_in, const int* in_sizes, int n_in,
                              void* d_out, int out_size, void* d_ws, size_t ws_size,
                              hipStream_t stream)
{
    (void)in_sizes; (void)n_in; (void)d_ws; (void)ws_size; (void)out_size;
    lstm_mfma<<<NB, NT, 0, stream>>>(
        (const float*)d_in[0],
        (const float*)d_in[1], (const float*)d_in[2],
        (const float*)d_in[3], (const float*)d_in[4],
        (const float*)d_in[5], (const float*)d_in[6],
        (const float*)d_in[7], (const float*)d_in[8],
        (const float*)d_in[9], (const float*)d_in[10],
        (const float*)d_in[11], (const float*)d_in[12],
        (float*)d_out);
}